// Round 5
// baseline (292.093 us; speedup 1.0000x reference)
//
#include <hip/hip_runtime.h>
#include <hip/hip_bf16.h>

// CARAFE fp32 pipeline v2. x(4,256,64,64), Wc(64,256), bc(64), We(100,64,3,3),
// be(100) -> out(4,256,128,128). All fp32 I/O.
//
// ws layout (fp32 elements):
//   comp  [4][64][66*66] zero-padded  @ 0          (1,115,136)
//   Wr    [ij4][cc64][q9][k pad28]    @ 1,115,136  (64,512)
//   mask  [e=ij*25+k][16384 px]       @ 1,179,648  (1,638,400)  transposed planes
// total 2,818,048 floats = 11,272,192 B (gate known to pass; fallback = fused).

#define COMP_F 0
#define WR_F   1115136
#define MSK_F  1179648
#define WS_NEED 11272192ull
#define CSTR 4356  // 66*66

// ---- K0: We relayout + comp halo zeroing ----
__global__ void k0_prep(const float* __restrict__ We, float* __restrict__ ws) {
    int tid = blockIdx.x * blockDim.x + threadIdx.x;
    if (tid < 57600) {  // Wr[ij][cc][q][k28] = We[4k+ij][cc*9+q]
        int k = tid % 25, q = (tid / 25) % 9, cc = (tid / 225) % 64, ij = tid / 14400;
        ws[WR_F + (((size_t)(ij * 64 + cc) * 9) + q) * 28 + k] =
            We[(size_t)(4 * k + ij) * 576 + cc * 9 + q];
    }
    if (tid < 66560) {  // zero the 1-wide border of each 66x66 comp plane
        int nc = tid / 260, r = tid % 260;
        int row, col;
        if (r < 66)       { row = 0;           col = r; }
        else if (r < 132) { row = 65;          col = r - 66; }
        else if (r < 196) { row = r - 132 + 1; col = 0; }
        else              { row = r - 196 + 1; col = 65; }
        ws[COMP_F + (size_t)nc * CSTR + row * 66 + col] = 0.f;
    }
}

// ---- K1: 1x1 compressor, one x pass for all 64 cc ----
// grid 256 (n*64+h), block 256: lane=w, wave=ccg (16 cc each).
__global__ __launch_bounds__(256) void k1_comp(const float* __restrict__ x,
                                               const float* __restrict__ Wc,
                                               const float* __restrict__ bc,
                                               float* __restrict__ ws) {
    int b = blockIdx.x;
    int n = b >> 6, h = b & 63;
    int w   = threadIdx.x & 63;
    int ccg = threadIdx.x >> 6;  // wave-uniform
    int cc0 = ccg * 16;

    float acc[16];
#pragma unroll
    for (int u = 0; u < 16; ++u) acc[u] = 0.f;

    const float* xp = x + (size_t)n * 256 * 4096 + h * 64 + w;
#pragma unroll 8
    for (int c = 0; c < 256; ++c) {
        float xv = xp[(size_t)c * 4096];
#pragma unroll
        for (int u = 0; u < 16; ++u)
            acc[u] += xv * Wc[(cc0 + u) * 256 + c];  // uniform -> s_load
    }
#pragma unroll
    for (int u = 0; u < 16; ++u)
        ws[COMP_F + (size_t)(n * 64 + cc0 + u) * CSTR + (h + 1) * 66 + (w + 1)]
            = acc[u] + bc[cc0 + u];
}

// ---- K2: encoder + softmax, comp & weights in LDS, masks out ----
// grid 256 (n*64 + 8x8-tile), block 256: lane=px(8x8), wave=ij. 25 accs/thread.
__global__ __launch_bounds__(256) void k2_enc(const float* __restrict__ be,
                                              float* __restrict__ ws) {
    __shared__ float compS[6400];                 // 64cc x 10x10, 25.6 KB
    __shared__ __align__(16) float wS[4 * 8 * 9 * 28];  // 8-cc chunk, 32.3 KB
    int b = blockIdx.x;
    int n = b >> 6, tile = b & 63;
    int ty0 = (tile >> 3) * 8, tx0 = (tile & 7) * 8;
    int lane = threadIdx.x & 63, ij = threadIdx.x >> 6;  // ij wave-uniform
    int py = lane >> 3, pxx = lane & 7;

    const float* compn = ws + COMP_F + (size_t)n * 64 * CSTR;
    for (int e = threadIdx.x; e < 6400; e += 256) {
        int cc = e / 100, p = e % 100;
        compS[e] = compn[(size_t)cc * CSTR + (ty0 + p / 10) * 66 + (tx0 + p % 10)];
    }

    float acc[25];
#pragma unroll
    for (int k = 0; k < 25; ++k) acc[k] = be[4 * k + ij];

    const float4* WrB = (const float4*)(ws + WR_F);
    for (int cb = 0; cb < 64; cb += 8) {
        __syncthreads();  // covers comp staging (1st iter) and prior compute (WAR)
        for (int e = threadIdx.x; e < 2016; e += 256) {  // 504 f4 per ij
            int ij_ = e / 504, r = e % 504;
            ((float4*)wS)[e] = WrB[ij_ * 4032 + cb * 63 + r];
        }
        __syncthreads();
        const float* wij = wS + ij * (8 * 9 * 28);
#pragma unroll
        for (int c_ = 0; c_ < 8; ++c_) {
            int cc = cb + c_;
            float cv[9];
#pragma unroll
            for (int dy = 0; dy < 3; ++dy)
#pragma unroll
                for (int dx = 0; dx < 3; ++dx)
                    cv[dy * 3 + dx] = compS[cc * 100 + (py + dy) * 10 + (pxx + dx)];
            const float* wr = wij + c_ * 9 * 28;
#pragma unroll
            for (int q = 0; q < 9; ++q) {
                float v = cv[q];
                const float* row = wr + q * 28;  // 112B stride, 16B-aligned
#pragma unroll
                for (int kt = 0; kt < 6; ++kt) {
                    float4 w4 = *(const float4*)(row + 4 * kt);
                    acc[kt * 4 + 0] += v * w4.x;
                    acc[kt * 4 + 1] += v * w4.y;
                    acc[kt * 4 + 2] += v * w4.z;
                    acc[kt * 4 + 3] += v * w4.w;
                }
                acc[24] += v * row[24];
            }
        }
    }

    // softmax over 25 taps, store masks to transposed planes
    float mx = acc[0];
#pragma unroll
    for (int k = 1; k < 25; ++k) mx = fmaxf(mx, acc[k]);
    float s = 0.f;
#pragma unroll
    for (int k = 0; k < 25; ++k) { acc[k] = __expf(acc[k] - mx); s += acc[k]; }
    float inv = 1.f / s;
    int pix = n * 4096 + (ty0 + py) * 64 + (tx0 + pxx);
    float* mp = ws + MSK_F;
#pragma unroll
    for (int k = 0; k < 25; ++k)
        mp[(size_t)(ij * 25 + k) * 16384 + pix] = acc[k] * inv;
}

// ---- K3: reassembly. masks pre-softmaxed, coalesced plane reads ----
// grid 1024: b = chunk*256 + (n*64+tile). block 256: lane=px(8x8), wave=cl.
__global__ __launch_bounds__(256) void k3_out(const float* __restrict__ x,
                                              const float* __restrict__ ws,
                                              float* __restrict__ out) {
    __shared__ float xt[64 * 144];  // 64c x 12x12 halo, 36.9 KB
    int b = blockIdx.x;
    int chunk = b >> 8;           // same tile -> same XCD (b%8 preserved)
    int t6 = b & 255;
    int n = t6 >> 6, tile = t6 & 63;
    int ty0 = (tile >> 3) * 8, tx0 = (tile & 7) * 8;
    int c0 = chunk * 64;

    const float* xn = x + (size_t)(n * 256 + c0) * 4096;
    for (int e = threadIdx.x; e < 9216; e += 256) {
        int c_ = e / 144, p = e % 144;
        int hh = ty0 + p / 12 - 2, ww = tx0 + p % 12 - 2;
        float v = 0.f;
        if (hh >= 0 && hh < 64 && ww >= 0 && ww < 64)
            v = xn[(size_t)c_ * 4096 + hh * 64 + ww];
        xt[e] = v;
    }

    int lane = threadIdx.x & 63, cl = threadIdx.x >> 6;
    int py = lane >> 3, pxx = lane & 7;
    int pix = n * 4096 + (ty0 + py) * 64 + (tx0 + pxx);
    const float* mp = ws + MSK_F;
    float4 mk[25];
#pragma unroll
    for (int t = 0; t < 25; ++t) {
        mk[t].x = mp[(size_t)(t)*16384 + pix];
        mk[t].y = mp[(size_t)(25 + t) * 16384 + pix];
        mk[t].z = mp[(size_t)(50 + t) * 16384 + pix];
        mk[t].w = mp[(size_t)(75 + t) * 16384 + pix];
    }
    __syncthreads();

    int ce = cl * 16 + 16;
    for (int c_ = cl * 16; c_ < ce; ++c_) {
        const float* xc = xt + c_ * 144 + py * 12 + pxx;
        float a0 = 0.f, a1 = 0.f, a2 = 0.f, a3 = 0.f;
#pragma unroll
        for (int t = 0; t < 25; ++t) {
            float v = xc[(t / 5) * 12 + (t % 5)];
            a0 += v * mk[t].x; a1 += v * mk[t].y;
            a2 += v * mk[t].z; a3 += v * mk[t].w;
        }
        size_t ob = ((size_t)(n * 256 + c0 + c_) * 128 + 2 * (ty0 + py)) * 128
                  + 2 * (tx0 + pxx);
        float2 r0 = {a0, a1}, r1 = {a2, a3};
        *(float2*)(out + ob)       = r0;
        *(float2*)(out + ob + 128) = r1;
    }
}

// ---- Fallback: round-3 fused kernel (known-passing, 504 us) ----
__global__ __launch_bounds__(256) void k_fused(const float* __restrict__ x,
                                               const float* __restrict__ Wc,
                                               const float* __restrict__ bc,
                                               const float* __restrict__ We,
                                               const float* __restrict__ be,
                                               float* __restrict__ out) {
    __shared__ float compS[64 * 101];
    int n = blockIdx.x >> 6, tile = blockIdx.x & 63;
    int ty0 = (tile >> 3) * 8, tx0 = (tile & 7) * 8;
    const float* xn = x + (size_t)n * 256 * 4096;
    {
        int pa = threadIdx.x & 127;
        int ga = __builtin_amdgcn_readfirstlane(threadIdx.x >> 7);
        bool act = pa < 100;
        int ah = ty0 + pa / 10 - 1, aw = tx0 + pa % 10 - 1;
        bool inb = act && ah >= 0 && ah < 64 && aw >= 0 && aw < 64;
        int xoff = ah * 64 + aw;
        float acc[32];
#pragma unroll
        for (int i = 0; i < 32; ++i) acc[i] = 0.f;
        for (int c = 0; c < 256; ++c) {
            float xv = inb ? xn[(size_t)c * 4096 + xoff] : 0.f;
#pragma unroll
            for (int i = 0; i < 32; ++i) acc[i] += xv * Wc[(ga * 32 + i) * 256 + c];
        }
        if (act)
#pragma unroll
            for (int i = 0; i < 32; ++i) {
                int cc = ga * 32 + i;
                compS[cc * 101 + pa] = inb ? acc[i] + bc[cc] : 0.f;
            }
    }
    __syncthreads();
    int px = threadIdx.x & 63;
    int ij = __builtin_amdgcn_readfirstlane(threadIdx.x >> 6);
    int py = px >> 3, pxx = px & 7;
    int h = ty0 + py, w = tx0 + pxx;
    float m[25];
#pragma unroll
    for (int k = 0; k < 25; ++k) m[k] = be[4 * k + ij];
    for (int cc = 0; cc < 64; ++cc) {
        float cv[9];
#pragma unroll
        for (int dy = 0; dy < 3; ++dy)
#pragma unroll
            for (int dx = 0; dx < 3; ++dx)
                cv[dy * 3 + dx] = compS[cc * 101 + (py + dy) * 10 + (pxx + dx)];
        int base = cc * 9;
#pragma unroll
        for (int k = 0; k < 25; ++k) {
            int eb = (4 * k + ij) * 576 + base;
            float s = 0.f;
#pragma unroll
            for (int qb = 0; qb < 9; ++qb) s += cv[qb] * We[eb + qb];
            m[k] += s;
        }
    }
    float mxv = m[0];
#pragma unroll
    for (int k = 1; k < 25; ++k) mxv = fmaxf(mxv, m[k]);
    float ss = 0.f;
#pragma unroll
    for (int k = 0; k < 25; ++k) { m[k] = __expf(m[k] - mxv); ss += m[k]; }
    float inv = 1.f / ss;
#pragma unroll
    for (int k = 0; k < 25; ++k) m[k] *= inv;
    int offs[25];
    unsigned vm = 0;
#pragma unroll
    for (int t = 0; t < 25; ++t) {
        int hh = h + t / 5 - 2, ww = w + t % 5 - 2;
        bool v = hh >= 0 && hh < 64 && ww >= 0 && ww < 64;
        offs[t] = v ? hh * 64 + ww : 0;
        if (v) vm |= 1u << t;
    }
    size_t outp = ((size_t)n * 256 * 128 + (2 * h + (ij >> 1))) * 128 + (2 * w + (ij & 1));
    for (int c = 0; c < 256; ++c) {
        const float* xc = xn + (size_t)c * 4096;
        float sum = 0.f;
#pragma unroll
        for (int t = 0; t < 25; ++t) {
            float v = ((vm >> t) & 1u) ? xc[offs[t]] : 0.f;
            sum += v * m[t];
        }
        out[outp + (size_t)c * 16384] = sum;
    }
}

extern "C" void kernel_launch(void* const* d_in, const int* in_sizes, int n_in,
                              void* d_out, int out_size, void* d_ws, size_t ws_size,
                              hipStream_t stream) {
    const float* x  = (const float*)d_in[0];
    const float* Wc = (const float*)d_in[1];
    const float* bc = (const float*)d_in[2];
    const float* We = (const float*)d_in[3];
    const float* be = (const float*)d_in[4];
    float* out = (float*)d_out;

    if (ws_size >= WS_NEED && d_ws != nullptr) {
        float* ws = (float*)d_ws;
        hipLaunchKernelGGL(k0_prep, dim3(260),  dim3(256), 0, stream, We, ws);
        hipLaunchKernelGGL(k1_comp, dim3(256),  dim3(256), 0, stream, x, Wc, bc, ws);
        hipLaunchKernelGGL(k2_enc,  dim3(256),  dim3(256), 0, stream, be, ws);
        hipLaunchKernelGGL(k3_out,  dim3(1024), dim3(256), 0, stream, x, ws, out);
    } else {
        hipLaunchKernelGGL(k_fused, dim3(256),  dim3(256), 0, stream,
                           x, Wc, bc, We, be, out);
    }
}

// Round 6
// 214.512 us; speedup vs baseline: 1.3617x; 1.3617x over previous
//
#include <hip/hip_runtime.h>
#include <hip/hip_bf16.h>

// CARAFE fp32 pipeline v3. x(4,256,64,64), Wc(64,256), bc(64), We(100,64,3,3),
// be(100) -> out(4,256,128,128). All fp32 I/O.
//
// ws layout (fp32 elements):
//   comp  [4][64][66*66] zero-padded  @ 0          (1,115,136)
//   Wr    [ij4][cc64][q9][k pad28]    @ 1,115,136  (64,512)
//   logit [e=ij*25+k][16384 px]       @ 1,179,648  (1,638,400)  transposed planes,
//                                     prefilled with be[e], K2 atomicAdds partials.
// total 2,818,048 floats = 11,272,192 B (gate known to pass; fallback = fused).

#define COMP_F 0
#define WR_F   1115136
#define LOG_F  1179648
#define WS_NEED 11272192ull
#define CSTR 4356  // 66*66

// ---- K0: We relayout + comp halo zeroing + logit be-prefill ----
__global__ __launch_bounds__(256) void k0_prep(const float* __restrict__ We,
                                               const float* __restrict__ be,
                                               float* __restrict__ ws) {
    int tid = blockIdx.x * blockDim.x + threadIdx.x;
    if (tid < 57600) {  // Wr[ij][cc][q][k28] = We[4k+ij][cc*9+q]
        int k = tid % 25, q = (tid / 25) % 9, cc = (tid / 225) % 64, ij = tid / 14400;
        ws[WR_F + (((size_t)(ij * 64 + cc) * 9) + q) * 28 + k] =
            We[(size_t)(4 * k + ij) * 576 + cc * 9 + q];
    }
    if (tid < 66560) {  // zero the 1-wide border of each 66x66 comp plane
        int nc = tid / 260, r = tid % 260;
        int row, col;
        if (r < 66)       { row = 0;           col = r; }
        else if (r < 132) { row = 65;          col = r - 66; }
        else if (r < 196) { row = r - 132 + 1; col = 0; }
        else              { row = r - 196 + 1; col = 65; }
        ws[COMP_F + (size_t)nc * CSTR + row * 66 + col] = 0.f;
    }
    // logit prefill: 100 planes x 16384 = 409600 float4 stores
    if (tid < 409600) {
        int plane = tid >> 12;            // tid / 4096 (4096 f4 per plane)
        float b = be[plane];              // uniform per 4096 -> s_load
        float4 v = {b, b, b, b};
        ((float4*)(ws + LOG_F))[tid] = v;
    }
}

// ---- K1: 1x1 compressor, cc-half split for occupancy ----
// grid 512: b = n*128 + h*2 + half. block 256 = w64 x ccg4 (8 cc each).
__global__ __launch_bounds__(256, 2) void k1_comp(const float* __restrict__ x,
                                                  const float* __restrict__ Wc,
                                                  const float* __restrict__ bc,
                                                  float* __restrict__ ws) {
    int b = blockIdx.x;
    int half = b & 1, h = (b >> 1) & 63, n = b >> 7;
    int w   = threadIdx.x & 63;
    int ccg = threadIdx.x >> 6;            // wave-uniform
    int cc0 = half * 32 + ccg * 8;

    float acc[8];
#pragma unroll
    for (int u = 0; u < 8; ++u) acc[u] = 0.f;

    const float* xp = x + (size_t)n * 256 * 4096 + h * 64 + w;
#pragma unroll 8
    for (int c = 0; c < 256; ++c) {
        float xv = xp[(size_t)c * 4096];
#pragma unroll
        for (int u = 0; u < 8; ++u)
            acc[u] += xv * Wc[(cc0 + u) * 256 + c];  // uniform -> s_load
    }
#pragma unroll
    for (int u = 0; u < 8; ++u)
        ws[COMP_F + (size_t)(n * 64 + cc0 + u) * CSTR + (h + 1) * 66 + (w + 1)]
            = acc[u] + bc[cc0 + u];
}

// ---- K2: 3x3 encoder, cc-half split, atomicAdd partial logits ----
// grid 512: b = n*128 + t16*8 + ij*2 + half. block 256 = 16x16 px.
__global__ __launch_bounds__(256, 2) void k2_enc(float* __restrict__ ws) {
    __shared__ float compS[32 * 342];              // 32cc x 18r x 19c, 43.8 KB
    __shared__ __align__(16) float wS[32 * 252];   // 32cc x 9q x 28k, 32.3 KB
    int b = blockIdx.x;
    int half = b & 1, ij = (b >> 1) & 3, t = (b >> 3) & 15, n = b >> 7;
    int ty0 = (t >> 2) * 16, tx0 = (t & 3) * 16;
    int py = threadIdx.x >> 4, px = threadIdx.x & 15;

    // stage comp half-tile (18x18 of the padded 66x66 planes)
    const float* compn = ws + COMP_F + (size_t)(n * 64 + half * 32) * CSTR;
    for (int e = threadIdx.x; e < 32 * 324; e += 256) {
        int cc = e / 324, r = (e % 324) / 18, cl = e % 18;
        compS[cc * 342 + r * 19 + cl] = compn[(size_t)cc * CSTR + (ty0 + r) * 66 + (tx0 + cl)];
    }
    // stage weight half (32cc x 252)
    const float4* wsrc = (const float4*)(ws + WR_F + (size_t)(ij * 64 + half * 32) * 252);
    for (int e = threadIdx.x; e < 2016; e += 256)
        ((float4*)wS)[e] = wsrc[e];
    __syncthreads();

    float acc[25];
#pragma unroll
    for (int k = 0; k < 25; ++k) acc[k] = 0.f;

#pragma unroll 2
    for (int cc = 0; cc < 32; ++cc) {
        float cv[9];
#pragma unroll
        for (int dy = 0; dy < 3; ++dy)
#pragma unroll
            for (int dx = 0; dx < 3; ++dx)
                cv[dy * 3 + dx] = compS[cc * 342 + (py + dy) * 19 + (px + dx)];
        const float* wr = wS + cc * 252;
#pragma unroll
        for (int q = 0; q < 9; ++q) {
            float v = cv[q];
            const float* row = wr + q * 28;
#pragma unroll
            for (int kt = 0; kt < 6; ++kt) {
                float4 w4 = *(const float4*)(row + 4 * kt);
                acc[kt * 4 + 0] += v * w4.x;
                acc[kt * 4 + 1] += v * w4.y;
                acc[kt * 4 + 2] += v * w4.z;
                acc[kt * 4 + 3] += v * w4.w;
            }
            acc[24] += v * row[24];
        }
    }

    int pix = n * 4096 + (ty0 + py) * 64 + (tx0 + px);
    float* lp = ws + LOG_F;
#pragma unroll
    for (int k = 0; k < 25; ++k)
        atomicAdd(&lp[(size_t)(ij * 25 + k) * 16384 + pix], acc[k]);
}

// ---- K3: softmax (in-thread) + reassembly, band-structured ----
// grid 512: b = n*128 + band*8 + chunk. block 512 = w64 x hsub4 x i2.
__global__ __launch_bounds__(512, 4) void k3_out(const float* __restrict__ x,
                                                 const float* __restrict__ ws,
                                                 float* __restrict__ out) {
    __shared__ float xt[32 * 544];  // 32c x 8rows x 68cols, 69.6 KB
    int b = blockIdx.x;
    int chunk = b & 7, band = (b >> 3) & 15, n = b >> 7;
    int h0 = band * 4, c0 = chunk * 32;

    int w    = threadIdx.x & 63;
    int hsub = (threadIdx.x >> 6) & 3;
    int i    = threadIdx.x >> 8;

    // logits (be-prefilled + K2 partials): 50 coalesced plane loads
    int pix = n * 4096 + (h0 + hsub) * 64 + w;
    const float* lp = ws + LOG_F;
    float mk0[25], mk1[25];
#pragma unroll
    for (int t = 0; t < 25; ++t) {
        mk0[t] = lp[(size_t)((i * 2 + 0) * 25 + t) * 16384 + pix];
        mk1[t] = lp[(size_t)((i * 2 + 1) * 25 + t) * 16384 + pix];
    }

    // stage x chunk: rows h0-2..h0+5, cols -2..65, 32 channels
    const float* xn = x + (size_t)(n * 256 + c0) * 4096;
    for (int e = threadIdx.x; e < 32 * 544; e += 512) {
        int c_ = e / 544, rem = e % 544;
        int r = rem / 68, cl = rem % 68;
        int hh = h0 - 2 + r, ww = cl - 2;
        float v = 0.f;
        if (hh >= 0 && hh < 64 && ww >= 0 && ww < 64)
            v = xn[(size_t)c_ * 4096 + hh * 64 + ww];
        xt[e] = v;
    }

    // softmax over 25 taps for the two ij this thread owns
    {
        float mx0 = mk0[0], mx1 = mk1[0];
#pragma unroll
        for (int t = 1; t < 25; ++t) { mx0 = fmaxf(mx0, mk0[t]); mx1 = fmaxf(mx1, mk1[t]); }
        float s0 = 0.f, s1 = 0.f;
#pragma unroll
        for (int t = 0; t < 25; ++t) {
            mk0[t] = __expf(mk0[t] - mx0); s0 += mk0[t];
            mk1[t] = __expf(mk1[t] - mx1); s1 += mk1[t];
        }
        float i0 = 1.f / s0, i1 = 1.f / s1;
#pragma unroll
        for (int t = 0; t < 25; ++t) { mk0[t] *= i0; mk1[t] *= i1; }
    }
    __syncthreads();

    size_t orow = ((size_t)(n * 256 + c0) * 128 + 2 * (h0 + hsub) + i) * 128 + 2 * w;
    for (int c_ = 0; c_ < 32; ++c_) {
        const float* xc = xt + c_ * 544 + hsub * 68 + w;
        float a0 = 0.f, a1 = 0.f;
#pragma unroll
        for (int dy = 0; dy < 5; ++dy) {
            const float* xr = xc + dy * 68;
#pragma unroll
            for (int dx = 0; dx < 5; ++dx) {
                float v = xr[dx];
                int t = dy * 5 + dx;
                a0 += v * mk0[t];
                a1 += v * mk1[t];
            }
        }
        float2 r = {a0, a1};
        *(float2*)(out + orow + (size_t)c_ * 16384) = r;
    }
}

// ---- Fallback: round-3 fused kernel (known-passing) ----
__global__ __launch_bounds__(256) void k_fused(const float* __restrict__ x,
                                               const float* __restrict__ Wc,
                                               const float* __restrict__ bc,
                                               const float* __restrict__ We,
                                               const float* __restrict__ be,
                                               float* __restrict__ out) {
    __shared__ float compS[64 * 101];
    int n = blockIdx.x >> 6, tile = blockIdx.x & 63;
    int ty0 = (tile >> 3) * 8, tx0 = (tile & 7) * 8;
    const float* xn = x + (size_t)n * 256 * 4096;
    {
        int pa = threadIdx.x & 127;
        int ga = __builtin_amdgcn_readfirstlane(threadIdx.x >> 7);
        bool act = pa < 100;
        int ah = ty0 + pa / 10 - 1, aw = tx0 + pa % 10 - 1;
        bool inb = act && ah >= 0 && ah < 64 && aw >= 0 && aw < 64;
        int xoff = ah * 64 + aw;
        float acc[32];
#pragma unroll
        for (int i = 0; i < 32; ++i) acc[i] = 0.f;
        for (int c = 0; c < 256; ++c) {
            float xv = inb ? xn[(size_t)c * 4096 + xoff] : 0.f;
#pragma unroll
            for (int i = 0; i < 32; ++i) acc[i] += xv * Wc[(ga * 32 + i) * 256 + c];
        }
        if (act)
#pragma unroll
            for (int i = 0; i < 32; ++i) {
                int cc = ga * 32 + i;
                compS[cc * 101 + pa] = inb ? acc[i] + bc[cc] : 0.f;
            }
    }
    __syncthreads();
    int px = threadIdx.x & 63;
    int ij = __builtin_amdgcn_readfirstlane(threadIdx.x >> 6);
    int py = px >> 3, pxx = px & 7;
    int h = ty0 + py, w = tx0 + pxx;
    float m[25];
#pragma unroll
    for (int k = 0; k < 25; ++k) m[k] = be[4 * k + ij];
    for (int cc = 0; cc < 64; ++cc) {
        float cv[9];
#pragma unroll
        for (int dy = 0; dy < 3; ++dy)
#pragma unroll
            for (int dx = 0; dx < 3; ++dx)
                cv[dy * 3 + dx] = compS[cc * 101 + (py + dy) * 10 + (pxx + dx)];
        int base = cc * 9;
#pragma unroll
        for (int k = 0; k < 25; ++k) {
            int eb = (4 * k + ij) * 576 + base;
            float s = 0.f;
#pragma unroll
            for (int qb = 0; qb < 9; ++qb) s += cv[qb] * We[eb + qb];
            m[k] += s;
        }
    }
    float mxv = m[0];
#pragma unroll
    for (int k = 1; k < 25; ++k) mxv = fmaxf(mxv, m[k]);
    float ss = 0.f;
#pragma unroll
    for (int k = 0; k < 25; ++k) { m[k] = __expf(m[k] - mxv); ss += m[k]; }
    float inv = 1.f / ss;
#pragma unroll
    for (int k = 0; k < 25; ++k) m[k] *= inv;
    int offs[25];
    unsigned vm = 0;
#pragma unroll
    for (int t = 0; t < 25; ++t) {
        int hh = h + t / 5 - 2, ww = w + t % 5 - 2;
        bool v = hh >= 0 && hh < 64 && ww >= 0 && ww < 64;
        offs[t] = v ? hh * 64 + ww : 0;
        if (v) vm |= 1u << t;
    }
    size_t outp = ((size_t)n * 256 * 128 + (2 * h + (ij >> 1))) * 128 + (2 * w + (ij & 1));
    for (int c = 0; c < 256; ++c) {
        const float* xc = xn + (size_t)c * 4096;
        float sum = 0.f;
#pragma unroll
        for (int t = 0; t < 25; ++t) {
            float v = ((vm >> t) & 1u) ? xc[offs[t]] : 0.f;
            sum += v * m[t];
        }
        out[outp + (size_t)c * 16384] = sum;
    }
}

extern "C" void kernel_launch(void* const* d_in, const int* in_sizes, int n_in,
                              void* d_out, int out_size, void* d_ws, size_t ws_size,
                              hipStream_t stream) {
    const float* x  = (const float*)d_in[0];
    const float* Wc = (const float*)d_in[1];
    const float* bc = (const float*)d_in[2];
    const float* We = (const float*)d_in[3];
    const float* be = (const float*)d_in[4];
    float* out = (float*)d_out;

    if (ws_size >= WS_NEED && d_ws != nullptr) {
        float* ws = (float*)d_ws;
        hipLaunchKernelGGL(k0_prep, dim3(1600), dim3(256), 0, stream, We, be, ws);
        hipLaunchKernelGGL(k1_comp, dim3(512),  dim3(256), 0, stream, x, Wc, bc, ws);
        hipLaunchKernelGGL(k2_enc,  dim3(512),  dim3(256), 0, stream, ws);
        hipLaunchKernelGGL(k3_out,  dim3(512),  dim3(512), 0, stream, x, ws, out);
    } else {
        hipLaunchKernelGGL(k_fused, dim3(256),  dim3(256), 0, stream,
                           x, Wc, bc, We, be, out);
    }
}